// Round 2
// 357.439 us; speedup vs baseline: 1.0522x; 1.0522x over previous
//
#include <hip/hip_runtime.h>

// SemNN — twin-tower masked-pool encoder + classifier.
// B=4096, S=128, D=512, VOCAB=50000, NUM_LABELS=3.
// Confirmed: float inputs bf16 (detector keeps f32 fallback), ids int32,
// masks int-like, OUTPUT f32. ws usage: exactly 16 MB.
//
// Round 10 (= round 9 with the macro-pragma compile bug fixed):
//  * round 9 put `#pragma unroll` inside a #define body — preprocessor
//    error. Now _Pragma("unroll").
//  * pool merged into ONE 8192-block dispatch (side = blockIdx.x>>12).
//  * GEMM: 512 threads (8 waves, 4x2 grid of 32x32 wave tiles),
//    double-buffered LDS -> ONE barrier per K-step (was 2), prefetch issued
//    at iteration top so its latency window spans stores+frag reads+MFMA.
//    All verified index math kept: 40-u16 padded rows (8-access/bank floor),
//    B rotate-swizzle chunks, C/D layout col=lane&15 row=kq*4+r.
//  * __launch_bounds__(512,4) caps VGPR at 128 -> 2 blocks/CU, 4 waves/SIMD.

typedef unsigned short u16;
typedef __attribute__((ext_vector_type(8))) short short8;
typedef __attribute__((ext_vector_type(4))) float f32x4;

__device__ __forceinline__ float bfu2f(u16 u) {
    union { unsigned int i; float f; } v;
    v.i = ((unsigned int)u) << 16;
    return v.f;
}

__device__ __forceinline__ u16 f2bfu(float f) {
    union { float f; unsigned int i; } v;
    v.f = f;
    unsigned int x = v.i;
    x += 0x7fffu + ((x >> 16) & 1u);   // RNE
    return (u16)(x >> 16);
}

// tanh(x) = (e^{2x}-1)/(e^{2x}+1) using hw exp2; |x| clamped so e stays
// finite. ~1e-7 rel error, plenty for bf16-rounded outputs.
__device__ __forceinline__ float fast_tanh(float x) {
    float xc = fminf(fmaxf(x, -15.f), 15.f);
    float e = __builtin_amdgcn_exp2f(xc * 2.885390082f);  // 2*log2(e)*x
    return (e - 1.f) / (e + 1.f);
}

// Wave-collective dtype detection; every lane returns flags:
//   bit0: float tensors are bf16 (vs f32); bits2-3: mask type
//   0=int32, 1=byte-bool, 2=bf16, 3=f32
__device__ __forceinline__ int detect_wave(const u16* __restrict__ W,
                                           const unsigned int* __restrict__ m,
                                           int lane)
{
    int cnt = 0;
    int w01 = 1, b01 = 1, lo16 = 0;
    #pragma unroll
    for (int j = lane; j < 256; j += 64) {
        u16 u = W[1024 + 2 * j];
        int e = (u >> 7) & 0xFF;
        cnt += (e >= 0x6A && e <= 0x7E) ? 1 : 0;
        unsigned int v = m[j];
        w01 &= (v <= 1u) ? 1 : 0;
        b01 &= ((v & ~0x01010101u) == 0u) ? 1 : 0;
        lo16 |= ((v & 0xFFFFu) == 0x3F80u) ? 1 : 0;
    }
    #pragma unroll
    for (int off = 32; off > 0; off >>= 1) {
        cnt  += __shfl_down(cnt, off);
        w01  &= __shfl_down(w01, off);
        b01  &= __shfl_down(b01, off);
        lo16 |= __shfl_down(lo16, off);
    }
    int mtype;
    if (w01)        mtype = 0;
    else if (b01)   mtype = 1;
    else if (lo16)  mtype = 2;
    else            mtype = 3;
    int fl = ((cnt >= 128) ? 1 : 0) | (mtype << 2);
    return __shfl(fl, 0);
}

__device__ __forceinline__ int mask_nonzero(const void* __restrict__ msk,
                                            int idx, int mtype)
{
    switch (mtype) {
        case 0:  return ((const int*)msk)[idx] != 0;
        case 1:  return ((const unsigned char*)msk)[idx] != 0;
        case 2:  return ((const u16*)msk)[idx] != 0;
        default: return ((const unsigned int*)msk)[idx] != 0u;
    }
}

// ---------------------------------------------------------------------------
// Kernel 1: embedding gather + masked sum-pool for BOTH sides -> P [8192,512].
// 8192 blocks (one per output row; row>=4096 is side b), 128 threads = 2
// waves; lane owns 16B of the 1KB row; waves split tokens; LDS combine.
// Gather body unchanged from round 8 (measured BW floor).
// ---------------------------------------------------------------------------
__global__ __launch_bounds__(128) void pool_kernel(
    const int* __restrict__ ids_a, const int* __restrict__ ids_b,
    const void* __restrict__ mska, const void* __restrict__ mskb,
    const void* __restrict__ W, u16* __restrict__ P,
    const unsigned int* __restrict__ Mdet)
{
    __shared__ int s_ids[128];
    __shared__ int s_cnt;
    __shared__ int s_flags;
    __shared__ float sP[512];
    const int t = threadIdx.x;
    const int w = t >> 6;
    const int lane = t & 63;

    if (t == 0) s_cnt = 0;
    if (t < 64) {
        int fl = detect_wave((const u16*)W, Mdet, t);
        if (t == 0) s_flags = fl;
    }
    __syncthreads();
    const int  flags = s_flags;
    const bool isbf  = (flags & 1) != 0;
    const int  mtype = (flags >> 2) & 3;

    const int row = blockIdx.x;            // 0..8191
    const int r   = row & 4095;
    const int* __restrict__ ids = (row < 4096) ? ids_a : ids_b;
    const void* __restrict__ msk = (row < 4096) ? mska : mskb;

    int id = ids[r * 128 + t];
    int mk = mask_nonzero(msk, r * 128 + t, mtype);
    if (mk) {
        int idx = atomicAdd(&s_cnt, 1);
        s_ids[idx] = id;
    }
    __syncthreads();
    const int cnt = s_cnt;

    float acc[8] = {};
    if (isbf) {
        const u16* Wb = (const u16*)W;
        int j = w;
        for (; j + 6 < cnt; j += 8) {
            union { uint4 v; u16 s[8]; } r0, r1, r2, r3;
            r0.v = *(const uint4*)(Wb + (size_t)s_ids[j + 0] * 512 + lane * 8);
            r1.v = *(const uint4*)(Wb + (size_t)s_ids[j + 2] * 512 + lane * 8);
            r2.v = *(const uint4*)(Wb + (size_t)s_ids[j + 4] * 512 + lane * 8);
            r3.v = *(const uint4*)(Wb + (size_t)s_ids[j + 6] * 512 + lane * 8);
            #pragma unroll
            for (int i = 0; i < 8; ++i)
                acc[i] += bfu2f(r0.s[i]) + bfu2f(r1.s[i]) +
                          bfu2f(r2.s[i]) + bfu2f(r3.s[i]);
        }
        for (; j < cnt; j += 2) {
            union { uint4 v; u16 s[8]; } rr;
            rr.v = *(const uint4*)(Wb + (size_t)s_ids[j] * 512 + lane * 8);
            #pragma unroll
            for (int i = 0; i < 8; ++i) acc[i] += bfu2f(rr.s[i]);
        }
    } else {
        const float* Wf = (const float*)W;
        for (int j = w; j < cnt; j += 2) {
            const float* rp = Wf + (size_t)s_ids[j] * 512 + lane * 8;
            float4 a = *(const float4*)(rp + 0);
            float4 b = *(const float4*)(rp + 4);
            acc[0] += a.x; acc[1] += a.y; acc[2] += a.z; acc[3] += a.w;
            acc[4] += b.x; acc[5] += b.y; acc[6] += b.z; acc[7] += b.w;
        }
    }

    if (w == 0) {
        #pragma unroll
        for (int i = 0; i < 8; ++i) sP[lane * 8 + i] = acc[i];
    }
    __syncthreads();
    if (w == 1) {
        union { uint4 v; u16 s[8]; } o;
        #pragma unroll
        for (int i = 0; i < 8; ++i)
            o.s[i] = f2bfu(acc[i] + sP[lane * 8 + i]);
        *(uint4*)(P + (size_t)row * 512 + lane * 8) = o.v;
    }
}

// ---------------------------------------------------------------------------
// Kernel 2: bf16 MFMA GEMM + bias + tanh.  C = tanh(Acat @ B + bias).
// Block tile 128x64, BK=32, 8 waves (4x2), wave 32x32. MFMA 16x16x32 bf16.
// Double-buffered LDS (rows 40 u16 kept — verified bank floor), one barrier
// per K-step. Per iter: STORE next tile from regs -> buf[p^1], issue FETCH
// for tile+2, frag-read buf[p], 4 MFMA, barrier.
// ---------------------------------------------------------------------------
template<bool ISBF>
__device__ __forceinline__ void gemm_body(
    const u16* __restrict__ A, const u16* __restrict__ A2, int K1,
    const void* __restrict__ Bv, const void* __restrict__ biasv,
    u16* __restrict__ C, int N, int K,
    u16* __restrict__ As0, u16* __restrict__ Bs0)
{
    const int tid  = threadIdx.x;          // 0..511
    const int lane = tid & 63;
    const int wid = tid >> 6;              // 0..7
    const int wm  = (wid & 3) * 32;
    const int wn  = (wid >> 2) * 32;
    const int ar = tid >> 2;               // 0..127, one uint4 of A per thread
    const int ak = (tid & 3) * 8;
    const int bk = tid >> 3;               // B staging: threads 0..255 only
    const int jn = tid & 7;
    const int nb = jn * 8;
    const int bofs = (((bk >> 3) + jn) & 3) * 8 + (bk & 7);
    const int lm = lane & 15;
    const int kq = lane >> 4;
    const int kc = kq * 8;
    const int m0 = blockIdx.x * 128;
    const int n0 = blockIdx.y * 64;

    const u16*   Bb = (const u16*)Bv;
    const float* Bf = (const float*)Bv;

    f32x4 acc[2][2];
    #pragma unroll
    for (int i = 0; i < 2; ++i)
        #pragma unroll
        for (int j = 0; j < 2; ++j)
            acc[i][j] = (f32x4){0.f, 0.f, 0.f, 0.f};

    uint4 ra;
    uint4 rbb;
    float4 rf0, rf1;

    // fetch(k0): coalesced A (16B/lane, 4 lanes/row) + B (16B/lane, 8/row)
    #define FETCH(k0)                                                         \
    {                                                                         \
        const int kg = (k0) + ak;                                             \
        const u16* base = (kg < K1) ? (A + kg) : (A2 + (kg - K1));            \
        ra = *(const uint4*)(base + (size_t)(m0 + ar) * 512);                 \
        if (tid < 256) {                                                      \
            if constexpr (ISBF) {                                             \
                rbb = *(const uint4*)(Bb + (size_t)((k0) + bk) * N + n0 + nb);\
            } else {                                                          \
                const float* Bp = Bf + (size_t)((k0) + bk) * N + n0 + nb;     \
                rf0 = *(const float4*)(Bp + 0);                               \
                rf1 = *(const float4*)(Bp + 4);                               \
            }                                                                 \
        }                                                                     \
    }

    // store regs -> LDS buffer pp (A: one b128; B: 8 swizzled b16 stores)
    #define STORE(pp)                                                         \
    {                                                                         \
        *(uint4*)&As0[(pp) * 5120 + ar * 40 + ak] = ra;                       \
        if (tid < 256) {                                                      \
            u16 bvals[8];                                                     \
            if constexpr (ISBF) {                                             \
                union { uint4 v; u16 s[8]; } ub; ub.v = rbb;                  \
                _Pragma("unroll")                                             \
                for (int i = 0; i < 8; ++i) bvals[i] = ub.s[i];               \
            } else {                                                          \
                bvals[0] = f2bfu(rf0.x); bvals[1] = f2bfu(rf0.y);             \
                bvals[2] = f2bfu(rf0.z); bvals[3] = f2bfu(rf0.w);             \
                bvals[4] = f2bfu(rf1.x); bvals[5] = f2bfu(rf1.y);             \
                bvals[6] = f2bfu(rf1.z); bvals[7] = f2bfu(rf1.w);             \
            }                                                                 \
            _Pragma("unroll")                                                 \
            for (int i = 0; i < 8; ++i)                                       \
                Bs0[(pp) * 2560 + (nb + i) * 40 + bofs] = bvals[i];           \
        }                                                                     \
    }

    FETCH(0)
    STORE(0)
    FETCH(32)                              // K >= 64 always (512 or 1024)
    __syncthreads();

    int p = 0;
    for (int k0 = 0; k0 < K; k0 += 32) {
        if (k0 + 32 < K) {
            STORE(p ^ 1)                   // tile k0+32 (fetched last iter)
            if (k0 + 64 < K) FETCH(k0 + 64)  // in flight across this compute
        }

        const u16* Ap = As0 + p * 5120;
        const u16* Bp2 = Bs0 + p * 2560;
        short8 af[2], bf[2];
        #pragma unroll
        for (int i = 0; i < 2; ++i)
            af[i] = *(const short8*)&Ap[(wm + i * 16 + lm) * 40 + kc];
        #pragma unroll
        for (int j = 0; j < 2; ++j) {
            const int n = wn + j * 16 + lm;
            const int ch = ((kq + (n >> 3)) & 3) * 8;
            bf[j] = *(const short8*)&Bp2[n * 40 + ch];
        }
        #pragma unroll
        for (int i = 0; i < 2; ++i)
            #pragma unroll
            for (int j = 0; j < 2; ++j)
                acc[i][j] = __builtin_amdgcn_mfma_f32_16x16x32_bf16(
                    af[i], bf[j], acc[i][j], 0, 0, 0);

        if (k0 + 32 < K) __syncthreads();  // one barrier per K-step
        p ^= 1;
    }
    #undef FETCH
    #undef STORE

    // epilogue: bias + tanh + bf16 store
    #pragma unroll
    for (int j = 0; j < 2; ++j) {
        const int n = n0 + wn + j * 16 + lm;
        const float bsv = ISBF ? bfu2f(((const u16*)biasv)[n])
                               : ((const float*)biasv)[n];
        #pragma unroll
        for (int i = 0; i < 2; ++i) {
            #pragma unroll
            for (int r = 0; r < 4; ++r) {
                const int m = m0 + wm + i * 16 + kq * 4 + r;
                C[(size_t)m * N + n] = f2bfu(fast_tanh(acc[i][j][r] + bsv));
            }
        }
    }
}

__global__ __launch_bounds__(512, 4) void gemm_mfma(
    const u16* __restrict__ A, const u16* __restrict__ A2, int K1,
    const void* __restrict__ B, const void* __restrict__ bias,
    u16* __restrict__ C, int N, int K,
    const u16* __restrict__ Wdet, const unsigned int* __restrict__ Mdet)
{
    __shared__ __align__(16) u16 As[2 * 128 * 40];
    __shared__ __align__(16) u16 Bs[2 * 64 * 40];
    __shared__ int s_flags;

    if (threadIdx.x < 64) {
        int fl = detect_wave(Wdet, Mdet, threadIdx.x);
        if (threadIdx.x == 0) s_flags = fl;
    }
    __syncthreads();
    if (s_flags & 1) gemm_body<true >(A, A2, K1, B, bias, C, N, K, As, Bs);
    else             gemm_body<false>(A, A2, K1, B, bias, C, N, K, As, Bs);
}

// ---------------------------------------------------------------------------
// Kernel 3: logits GEMV  out[m,0:3] = H[m,:] @ W2 + b2 -> f32 out.
// ---------------------------------------------------------------------------
__global__ __launch_bounds__(64) void logits_kernel(
    const u16* __restrict__ H, const void* __restrict__ W2,
    const void* __restrict__ b2, float* __restrict__ out,
    const u16* __restrict__ Wdet, const unsigned int* __restrict__ Mdet)
{
    const int lane = threadIdx.x;
    const int fl = detect_wave(Wdet, Mdet, lane);
    const bool isbf = (fl & 1) != 0;

    const int m = blockIdx.x;
    union { uint4 v; u16 s[8]; } h;
    h.v = *(const uint4*)(H + (size_t)m * 512 + lane * 8);

    float a0 = 0.f, a1 = 0.f, a2 = 0.f;
    #pragma unroll
    for (int i = 0; i < 8; ++i) {
        const int k = lane * 8 + i;
        float x = bfu2f(h.s[i]);
        float w0, w1, w2;
        if (isbf) {
            const u16* Wb = (const u16*)W2;
            w0 = bfu2f(Wb[k * 3 + 0]); w1 = bfu2f(Wb[k * 3 + 1]); w2 = bfu2f(Wb[k * 3 + 2]);
        } else {
            const float* Wf = (const float*)W2;
            w0 = Wf[k * 3 + 0]; w1 = Wf[k * 3 + 1]; w2 = Wf[k * 3 + 2];
        }
        a0 += x * w0; a1 += x * w1; a2 += x * w2;
    }
    #pragma unroll
    for (int off = 32; off > 0; off >>= 1) {
        a0 += __shfl_down(a0, off);
        a1 += __shfl_down(a1, off);
        a2 += __shfl_down(a2, off);
    }
    if (lane == 0) {
        float b0, b1, b2v;
        if (isbf) {
            const u16* bb = (const u16*)b2;
            b0 = bfu2f(bb[0]); b1 = bfu2f(bb[1]); b2v = bfu2f(bb[2]);
        } else {
            const float* bf = (const float*)b2;
            b0 = bf[0]; b1 = bf[1]; b2v = bf[2];
        }
        out[m * 3 + 0] = a0 + b0;
        out[m * 3 + 1] = a1 + b1;
        out[m * 3 + 2] = a2 + b2v;
    }
}

// ---------------------------------------------------------------------------
extern "C" void kernel_launch(void* const* d_in, const int* in_sizes, int n_in,
                              void* d_out, int out_size, void* d_ws, size_t ws_size,
                              hipStream_t stream)
{
    const int* ids_a  = (const int*)d_in[0];
    const int* ids_b  = (const int*)d_in[1];
    const void* mask_a = d_in[2];
    const void* mask_b = d_in[3];
    const void* W_emb  = d_in[4];
    const void* enc_w1 = d_in[5];
    const void* enc_b1 = d_in[6];
    const void* enc_w2 = d_in[7];
    const void* enc_b2 = d_in[8];
    const void* cls_w1 = d_in[9];
    const void* cls_b1 = d_in[10];
    const void* cls_w2 = d_in[11];
    const void* cls_b2 = d_in[12];

    const u16* Wdet = (const u16*)W_emb;
    const unsigned int* Mdet = (const unsigned int*)mask_a;

    u16* buf0 = (u16*)d_ws;                          // 8192*512 bf16 = 8 MB
    u16* buf1 = buf0 + (size_t)8192 * 512;           // 8 MB  (total 16 MB)

    // pooled -> buf0 (rows 0..4095 side a, 4096..8191 side b), one dispatch
    pool_kernel<<<8192, 128, 0, stream>>>(ids_a, ids_b, mask_a, mask_b,
                                          W_emb, buf0, Mdet);

    // X1 = tanh(P @ enc_w1 + b1) -> buf1   [8192,512] x [512,512]
    gemm_mfma<<<dim3(64, 8), 512, 0, stream>>>(
        buf0, buf0, 512, enc_w1, enc_b1, buf1, 512, 512, Wdet, Mdet);

    // X2 = tanh(X1 @ enc_w2 + b2) -> buf0
    gemm_mfma<<<dim3(64, 8), 512, 0, stream>>>(
        buf1, buf1, 512, enc_w2, enc_b2, buf0, 512, 512, Wdet, Mdet);

    // H = tanh([va | vb] @ cls_w1 + b1) -> buf1   [4096,1024] x [1024,512]
    gemm_mfma<<<dim3(32, 8), 512, 0, stream>>>(
        buf0, buf0 + (size_t)4096 * 512, 512, cls_w1, cls_b1, buf1, 512, 1024, Wdet, Mdet);

    // logits -> d_out (f32)
    logits_kernel<<<4096, 64, 0, stream>>>(buf1, cls_w2, cls_b2, (float*)d_out, Wdet, Mdet);
}